// Round 3
// baseline (325.866 us; speedup 1.0000x reference)
//
#include <hip/hip_runtime.h>
#include <math.h>

#define UNITS 100000
#define BATCH 512
#define DIM 512
#define BN 64
#define NBLK ((UNITS + BN - 1) / BN)   /* 1563 */
#define SCALE 64.0f
#define COS_M2 0.87758256189037271612f  /* cos(0.5) */
#define SIN_M2 0.47942553860420300027f  /* sin(0.5) */
#define LOG2E  1.44269504088896340736f

typedef _Float16 half8 __attribute__((ext_vector_type(8)));
typedef float floatx4 __attribute__((ext_vector_type(4)));

// ---------------- Kernel 1: row-normalize inputs -> fragment-ordered fp16 A2 (x64) ----
__global__ void norm_emb_k(const float* __restrict__ inp, _Float16* __restrict__ A2) {
    const int row = blockIdx.x;
    const int lane = threadIdx.x;             // 64 threads = 1 wave
    const float* rp = inp + row * DIM + lane * 8;
    float v[8];
#pragma unroll
    for (int j = 0; j < 8; ++j) v[j] = rp[j];
    float ss = 0.f;
#pragma unroll
    for (int j = 0; j < 8; ++j) ss += v[j] * v[j];
#pragma unroll
    for (int off = 32; off > 0; off >>= 1) ss += __shfl_xor(ss, off);
    const float inv = SCALE / sqrtf(ss);      // fold s=64 into A
    half8 h;
#pragma unroll
    for (int j = 0; j < 8; ++j) h[j] = (_Float16)(v[j] * inv);
    const int idx = ((((row >> 4) * 16 + (lane >> 2)) * 64) + (row & 15) + 16 * (lane & 3)) * 8;
    *(half8*)(A2 + idx) = h;
}

// ---------------- Kernel 2: w-prep: w f32 -> w16 fragment-ordered + col inv-norms -----
// Block = one 64-col GEMM tile, full K=512. Transpose via padded f32 LDS quarter-tiles.
__global__ __launch_bounds__(256) void wprep_k(const float* __restrict__ w,
                                               _Float16* __restrict__ w16,
                                               float* __restrict__ cninv) {
    __shared__ float T[128 * 66];            // [k128][col64 +2 pad] f32, 33.8 KB
    const int t = threadIdx.x;
    const int blk = blockIdx.x;
    const int c0 = blk * BN;
    const int cl = (t & 31) * 2;             // col pair
    const int kr = t >> 5;                   // 0..7
    const bool cval = (c0 + cl + 1) < UNITS; // pair-granular validity (32-col tail ok)
    float sq0 = 0.f, sq1 = 0.f;

    for (int q = 0; q < 4; ++q) {
        // ---- read 128 k-rows x 64 cols (coalesced f2), stage to padded LDS ----
#pragma unroll
        for (int ps = 0; ps < 16; ++ps) {
            const int k = q * 128 + ps * 8 + kr;
            float2 rd = cval ? *(const float2*)(w + (size_t)k * UNITS + c0 + cl)
                             : make_float2(0.f, 0.f);
            sq0 += rd.x * rd.x;
            sq1 += rd.y * rd.y;
            *(float2*)&T[(ps * 8 + kr) * 66 + cl] = rd;
        }
        __syncthreads();
        // ---- copy-out in MFMA fragment order: granule = (ksl, rowg, col) -> 8 halfs --
#pragma unroll
        for (int g = 0; g < 4; ++g) {
            const int G = t + 256 * g;       // 0..1023
            const int col = G & 63;
            const int rowg = (G >> 6) & 3;
            const int ksl = G >> 8;          // 0..3
            half8 h;
#pragma unroll
            for (int e = 0; e < 8; ++e)
                h[e] = (_Float16)T[(ksl * 32 + rowg * 8 + e) * 66 + col];
            const int off = blk * 32768 + (((q * 4 + ksl) * 4 + rowg) * 64 + col) * 8;
            *(half8*)(w16 + off) = h;        // contiguous 16B/lane -> 1KB/wave
        }
        __syncthreads();
    }
    // ---- column inv-norms (f32, matches reference) ----
    T[(t >> 5) * 66 + cl] = sq0;
    T[(t >> 5) * 66 + cl + 1] = sq1;
    __syncthreads();
    if (t < 64) {
        float s = 0.f;
#pragma unroll
        for (int gi = 0; gi < 8; ++gi) s += T[gi * 66 + t];
        cninv[c0 + t] = (s > 0.f) ? rsqrtf(s) : 1.0f;
    }
}

// ---------------- Kernel 3: GEMM (gload_lds staging) + margin + exp + partials --------
template<bool HALF>
__global__ __launch_bounds__(512, 4) void gemm2_k(
    const _Float16* __restrict__ w16, const _Float16* __restrict__ A2,
    const int* __restrict__ label, const float* __restrict__ cninv,
    float* __restrict__ outf, _Float16* __restrict__ vh,
    float* __restrict__ psum, float* __restrict__ pmax) {
    __shared__ char smem[73728];             // 64KB staging, reused as 72KB bounce
    _Float16* Bt = (_Float16*)smem;

    const int t = threadIdx.x;
    const int blk = blockIdx.x;
    const int c0 = blk * BN;
    const int wid = t >> 6;
    const int lane = t & 63;
    const int colg = lane & 15;
    const int rowg = lane >> 4;
    const int rowbase = wid * 64;

    // ---- stage 64KB w16 tile via global_load_lds (linear, no VALU, no conflicts) ----
    const char* gsrc = (const char*)w16 + (size_t)blk * 65536;
#pragma unroll
    for (int j = 0; j < 8; ++j) {
        const int chunk = wid * 8 + j;
        __builtin_amdgcn_global_load_lds(
            (const __attribute__((address_space(1))) void*)(gsrc + chunk * 1024 + lane * 16),
            (__attribute__((address_space(3))) void*)(smem + chunk * 1024 + lane * 16),
            16, 0, 0);
    }

    float cn[4];
#pragma unroll
    for (int nf = 0; nf < 4; ++nf) cn[nf] = cninv[c0 + nf * 16 + colg];

    asm volatile("s_waitcnt vmcnt(0)" ::: "memory");
    __syncthreads();

    floatx4 acc[4][4];
#pragma unroll
    for (int mf = 0; mf < 4; ++mf)
#pragma unroll
        for (int nf = 0; nf < 4; ++nf) acc[mf][nf] = (floatx4){0.f, 0.f, 0.f, 0.f};

#pragma unroll 4
    for (int ks = 0; ks < 16; ++ks) {
        half8 b[4];
#pragma unroll
        for (int nf = 0; nf < 4; ++nf)
            b[nf] = *(const half8*)(Bt + ((ks * 4 + rowg) * 64 + nf * 16 + colg) * 8);
#pragma unroll
        for (int mf = 0; mf < 4; ++mf) {
            const half8 a = *(const half8*)(A2 + (((wid * 4 + mf) * 16 + ks) * 64 + lane) * 8);
#pragma unroll
            for (int nf = 0; nf < 4; ++nf)
                acc[mf][nf] = __builtin_amdgcn_mfma_f32_16x16x32_f16(a, b[nf], acc[mf][nf], 0, 0, 0);
        }
    }
    __syncthreads();   // all Bt reads done before bounce overwrite

    // ---- epilogue: margin, per-(row,tile) max-shifted exp, bounce to LDS ----
    _Float16* bounce = (_Float16*)smem + wid * 4608;   // [64 rows][72] per wave
#pragma unroll
    for (int mf = 0; mf < 4; ++mf) {
#pragma unroll
        for (int r = 0; r < 4; ++r) {
            const int lrow = mf * 16 + rowg * 4 + r;
            const int R = rowbase + lrow;
            const int labv = label[R];
            float lg[4];
            float mx = -1e30f;
#pragma unroll
            for (int nf = 0; nf < 4; ++nf) {
                const int C = c0 + nf * 16 + colg;
                float x = acc[mf][nf][r] * cn[nf];     // 64*cos(theta)
                if (C == labv) {
                    float cs = fminf(1.f, fmaxf(-1.f, x * (1.0f / SCALE)));
                    x = SCALE * (cs * COS_M2 - sqrtf(fmaxf(0.f, 1.f - cs * cs)) * SIN_M2);
                }
                if (C >= UNITS) x = -1e30f;
                lg[nf] = x;
                mx = fmaxf(mx, x);
            }
            mx = fmaxf(mx, __shfl_xor(mx, 1));
            mx = fmaxf(mx, __shfl_xor(mx, 2));
            mx = fmaxf(mx, __shfl_xor(mx, 4));
            mx = fmaxf(mx, __shfl_xor(mx, 8));
            float s = 0.f;
#pragma unroll
            for (int nf = 0; nf < 4; ++nf) {
                const int C = c0 + nf * 16 + colg;
                const float e = exp2f((lg[nf] - mx) * LOG2E);
                s += (C < UNITS) ? e : 0.f;
                bounce[lrow * 72 + nf * 16 + colg] = (_Float16)e;
            }
            s += __shfl_xor(s, 1);
            s += __shfl_xor(s, 2);
            s += __shfl_xor(s, 4);
            s += __shfl_xor(s, 8);
            if (colg == 0) {
                psum[R * NBLK + blk] = s;
                pmax[R * NBLK + blk] = mx;
            }
        }
    }
    __syncthreads();

    // ---- coalesced store: lane = (row8 x chunk8), 16B/lane contiguous per row ----
    const int rl = lane >> 3;
    const int ch = lane & 7;
#pragma unroll
    for (int p = 0; p < 8; ++p) {
        const int row_l = p * 8 + rl;
        const int Rg = rowbase + row_l;
        const int C8 = c0 + ch * 8;
        const half8 h = *(const half8*)((_Float16*)smem + wid * 4608 + row_l * 72 + ch * 8);
        if (C8 + 7 < UNITS) {
            if (HALF) {
                *(half8*)(vh + (size_t)Rg * UNITS + C8) = h;
            } else {
                float4 o1, o2;
                o1.x = (float)h[0]; o1.y = (float)h[1]; o1.z = (float)h[2]; o1.w = (float)h[3];
                o2.x = (float)h[4]; o2.y = (float)h[5]; o2.z = (float)h[6]; o2.w = (float)h[7];
                float* op = outf + (size_t)Rg * UNITS + C8;
                *(float4*)op = o1;
                *(float4*)(op + 4) = o2;
            }
        }
    }
}

// ---------------- Kernel 4: per-row global max + sum -> per-(row,tile) factor ---------
__global__ void rowfac_k(const float* __restrict__ psum, const float* __restrict__ pmax,
                         float* __restrict__ fac) {
    const int row = blockIdx.x;
    const int lane = threadIdx.x;   // 64
    float mx = -1e30f;
    for (int b = lane; b < NBLK; b += 64) mx = fmaxf(mx, pmax[row * NBLK + b]);
#pragma unroll
    for (int off = 32; off > 0; off >>= 1) mx = fmaxf(mx, __shfl_xor(mx, off));
    float s = 0.f;
    for (int b = lane; b < NBLK; b += 64)
        s += psum[row * NBLK + b] * exp2f((pmax[row * NBLK + b] - mx) * LOG2E);
#pragma unroll
    for (int off = 32; off > 0; off >>= 1) s += __shfl_xor(s, off);
    const float invS = 1.0f / s;
    for (int b = lane; b < NBLK; b += 64)
        fac[row * NBLK + b] = exp2f((pmax[row * NBLK + b] - mx) * LOG2E) * invS;
}

// ---------------- Kernel 5: scale ----------------
__global__ void scale_half_k(const _Float16* __restrict__ v, const float* __restrict__ fac,
                             float* __restrict__ out) {
    const int row = blockIdx.y;
    const int c = (blockIdx.x * 256 + threadIdx.x) * 8;
    if (c >= UNITS) return;
    const float f = fac[row * NBLK + (c >> 6)];
    const half8 h = *(const half8*)(v + (size_t)row * UNITS + c);
    float4 o1, o2;
    o1.x = (float)h[0] * f; o1.y = (float)h[1] * f; o1.z = (float)h[2] * f; o1.w = (float)h[3] * f;
    o2.x = (float)h[4] * f; o2.y = (float)h[5] * f; o2.z = (float)h[6] * f; o2.w = (float)h[7] * f;
    float* op = out + (size_t)row * UNITS + c;
    *(float4*)op = o1;
    *(float4*)(op + 4) = o2;
}

__global__ void scale_f32_k(float* __restrict__ out, const float* __restrict__ fac) {
    const int row = blockIdx.y;
    const int c = (blockIdx.x * 256 + threadIdx.x) * 8;
    if (c >= UNITS) return;
    const float f = fac[row * NBLK + (c >> 6)];
    float* op = out + (size_t)row * UNITS + c;
    float4 o1 = *(float4*)op;
    float4 o2 = *(float4*)(op + 4);
    o1.x *= f; o1.y *= f; o1.z *= f; o1.w *= f;
    o2.x *= f; o2.y *= f; o2.z *= f; o2.w *= f;
    *(float4*)op = o1;
    *(float4*)(op + 4) = o2;
}

extern "C" void kernel_launch(void* const* d_in, const int* in_sizes, int n_in,
                              void* d_out, int out_size, void* d_ws, size_t ws_size,
                              hipStream_t stream) {
    const float* inp   = (const float*)d_in[0];
    const int*   label = (const int*)d_in[1];
    const float* w     = (const float*)d_in[2];
    float* out = (float*)d_out;

    char* ws = (char*)d_ws;
    _Float16* A2   = (_Float16*)ws;                                   // 512 KB
    float* psum    = (float*)(ws + (1 << 20));                        // 3.2 MB
    float* pmax    = (float*)(ws + (1 << 20) + 4u * BATCH * NBLK);    // 3.2 MB
    float* fac     = (float*)(ws + (1 << 20) + 8u * BATCH * NBLK);    // 3.2 MB
    float* cninv   = (float*)(ws + (1 << 20) + 12u * BATCH * NBLK);   // 400 KB
    _Float16* w16  = (_Float16*)(ws + (16 << 20));                    // 102.4 MB
    _Float16* vh   = (_Float16*)(ws + (size_t)(16 << 20) + (size_t)NBLK * 65536);
    const size_t need = (size_t)(16 << 20) + (size_t)NBLK * 65536 + (size_t)BATCH * UNITS * 2;
    const bool half_path = ws_size >= need;

    norm_emb_k<<<BATCH, 64, 0, stream>>>(inp, A2);
    wprep_k<<<NBLK, 256, 0, stream>>>(w, w16, cninv);
    if (half_path)
        gemm2_k<true><<<NBLK, 512, 0, stream>>>(w16, A2, label, cninv, out, vh, psum, pmax);
    else
        gemm2_k<false><<<NBLK, 512, 0, stream>>>(w16, A2, label, cninv, out, vh, psum, pmax);
    rowfac_k<<<BATCH, 64, 0, stream>>>(psum, pmax, fac);
    dim3 sg((UNITS + 2047) / 2048, BATCH);
    if (half_path)
        scale_half_k<<<sg, 256, 0, stream>>>(vh, fac, out);
    else
        scale_f32_k<<<sg, 256, 0, stream>>>(out, fac);
}